// Round 1
// baseline (114.571 us; speedup 1.0000x reference)
//
#include <hip/hip_runtime.h>
#include <math.h>

#define NS 4096
#define NT 4096

// Faithful port of CubicStretching._solve_depressed_cubic (hyperbolic formula),
// computed in f64. NOT assumed to be a true cubic root — replicate exactly.
__device__ __forceinline__ double cubic_root(double Q) {
    const double p = 6.0;                 // CHI
    const double q = p * Q;               // CHI * Q
    const double sp = sqrt(p);
    double arg = fabs(q) / (2.0 * p * sp / (3.0 * sqrt(3.0)));
    arg = fmax(1.0, arg);
    const double c = 2.0 * sp * cosh(acosh(arg) / 3.0);
    return (q >= 0.0) ? -c : c;
}

__device__ __forceinline__ double block_reduce(double v, int tid) {
    #pragma unroll
    for (int off = 32; off > 0; off >>= 1)
        v += __shfl_down(v, off, 64);
    __shared__ double lds[4];
    const int lane = tid & 63, wv = tid >> 6;
    if (lane == 0) lds[wv] = v;
    __syncthreads();
    return lds[0] + lds[1] + lds[2] + lds[3];   // valid in thread 0
}

// One block per row i. 256 threads x 4 interleaved float4 groups cover NT=4096.
__global__ __launch_bounds__(256) void bs_main(const float* __restrict__ V,
                                               double* __restrict__ part) {
    const int i   = blockIdx.x;
    const int tid = threadIdx.x;

    // ---- per-row stretch metrics (f64 -> f32), faithful to reference ----
    const double DU = 1.0 / (double)(NS - 1);
    const double C1 = cubic_root((100.0 - 0.0)   / 30.0);   // (B - 0)/ALPHA_STR
    const double C2 = cubic_root((100.0 - 300.0) / 30.0);   // (B - S_MAX)/ALPHA_STR
    const double u  = (double)i * DU;
    const double L  = C2 * u + C1 * (1.0 - u);
    const double dL = C2 - C1;
    const double S   = 100.0 + 30.0 * (L * L * L / 6.0 + L);
    const double dS  = 30.0 * dL * (0.5 * L * L + 1.0);
    const double d2S = 30.0 * dL * dL * L;

    const float Sn     = (float)(S   / 300.0);
    const float Sun    = (float)(dS  / 300.0);
    const float Suun   = (float)(d2S / 300.0);
    const float invSun  = 1.0f / Sun;
    const float invSun3 = invSun * invSun * invSun;
    const float Sn2 = Sn * Sn;
    const float AL  = 2.5f;            // 2r/sigma^2
    const float ASn = AL * Sn;

    const float INV2DU = 2047.5f;      // 1/(2*DU)
    const float INVDU2 = 16769025.0f;  // 1/DU^2 = 4095^2 (exact in f32)
    const float INV2DT = 102375.0f;    // 1/(2*DT_NORM) = 4095/0.04 (exact)

    const float* __restrict__ rowc = V + (size_t)i * NT;
    const bool inti = (i >= 1) && (i <= NS - 2);

    double pde = 0.0, bc = 0.0, tc = 0.0;

    #pragma unroll
    for (int s = 0; s < 4; ++s) {
        const int j0 = (tid + 256 * s) * 4;
        const float4 c = *(const float4*)(rowc + j0);
        const float cc[4] = {c.x, c.y, c.z, c.w};

        if (inti) {
            const float4 up4 = *(const float4*)(rowc - NT + j0);
            const float4 dn4 = *(const float4*)(rowc + NT + j0);
            const float uu[4] = {up4.x, up4.y, up4.z, up4.w};
            const float dd[4] = {dn4.x, dn4.y, dn4.z, dn4.w};
            const float lf = (j0 > 0)      ? rowc[j0 - 1] : 0.0f;  // L1 hit
            const float rt = (j0 + 4 < NT) ? rowc[j0 + 4] : 0.0f;  // L1 hit

            #pragma unroll
            for (int k = 0; k < 4; ++k) {
                const int j = j0 + k;
                if (j >= 1 && j <= NT - 2) {
                    const float cm = (k == 0) ? lf : cc[k - 1];
                    const float cp = (k == 3) ? rt : cc[k + 1];
                    const float Vu  = (dd[k] - uu[k]) * INV2DU;
                    const float Vuu = (dd[k] - 2.0f * cc[k] + uu[k]) * INVDU2;
                    const float Vt  = (cp - cm) * INV2DT;
                    const float VS  = Vu * invSun;
                    float VSS = (Vuu * Sun - Vu * Suun) * invSun3;
                    VSS = fminf(fmaxf(VSS, -100.0f), 100.0f);
                    const float r = Vt - Sn2 * VSS - ASn * VS + AL * cc[k];
                    pde += (double)(r * r);
                }
            }
        }

        if (i == NS - 1) {
            // far-field BC at S=Smax: target = 1 - (K/S_MAX) * exp(-R*(1-t))
            #pragma unroll
            for (int k = 0; k < 4; ++k) {
                const int j = j0 + k;
                const float t   = (float)j * (1.0f / (float)(NT - 1));
                const float tgt = 1.0f - (100.0f / 300.0f) * expf(-0.05f * (1.0f - t));
                const float d   = cc[k] - tgt;
                bc += (double)(d * d);
            }
        }

        if (j0 + 4 == NT) {
            // terminal condition element V[i, NT-1] (exactly one thread-group/row)
            const float ui = (float)u;
            const float x  = 50.0f * (ui - 100.0f / 300.0f);
            const float sp = fmaxf(x, 0.0f) + log1pf(expf(-fabsf(x)));  // softplus
            const float payoff = sp * (1.0f / 50.0f);
            const float d  = c.w - payoff;
            const float ad = fabsf(d);
            const float h  = (ad < 0.01f) ? 0.5f * d * d : 0.01f * (ad - 0.005f);
            tc += (double)h;
        }
    }

    const double n_int = (double)(NS - 2) * (double)(NT - 2);
    double contrib = pde * (1.0 / n_int)
                   + bc  * (10.0 / (double)NT)
                   + tc  * (10.0 / (double)NS);

    contrib = block_reduce(contrib, tid);
    if (tid == 0) part[i] = contrib;
}

__global__ __launch_bounds__(256) void bs_final(const double* __restrict__ part,
                                                float* __restrict__ out) {
    const int tid = threadIdx.x;
    double s = 0.0;
    for (int idx = tid; idx < NS; idx += 256) s += part[idx];
    s = block_reduce(s, tid);
    if (tid == 0) out[0] = (float)s;
}

extern "C" void kernel_launch(void* const* d_in, const int* in_sizes, int n_in,
                              void* d_out, int out_size, void* d_ws, size_t ws_size,
                              hipStream_t stream) {
    const float* V  = (const float*)d_in[0];
    float* out      = (float*)d_out;
    double* part    = (double*)d_ws;   // 4096 doubles = 32 KiB, all written each launch

    bs_main <<<NS, 256, 0, stream>>>(V, part);
    bs_final<<<1,  256, 0, stream>>>(part, out);
}

// Round 2
// 110.770 us; speedup vs baseline: 1.0343x; 1.0343x over previous
//
#include <hip/hip_runtime.h>
#include <math.h>

#define NS 4096
#define NT 4096

__device__ __forceinline__ double block_reduce(double v, int tid) {
    #pragma unroll
    for (int off = 32; off > 0; off >>= 1)
        v += __shfl_down(v, off, 64);
    __shared__ double lds[4];
    const int lane = tid & 63, wv = tid >> 6;
    if (lane == 0) lds[wv] = v;
    __syncthreads();
    return lds[0] + lds[1] + lds[2] + lds[3];   // valid in thread 0
}

// One block per row i. 256 threads x 4 interleaved float4 groups cover NT=4096.
// C1/C2 (the stretching-cubic roots) are computed ON HOST and passed in: they
// are compile-time constants of the problem; the f64 acosh/cosh per thread was
// the round-1 VALU hog.
__global__ __launch_bounds__(256) void bs_main(const float* __restrict__ V,
                                               double* __restrict__ part,
                                               double C1, double C2) {
    const int i   = blockIdx.x;
    const int tid = threadIdx.x;

    // ---- per-row stretch metrics (f64 polynomial -> f32), faithful to reference ----
    const double DU = 1.0 / (double)(NS - 1);
    const double u  = (double)i * DU;
    const double L  = C2 * u + C1 * (1.0 - u);
    const double dL = C2 - C1;
    const double S   = 100.0 + 30.0 * (L * L * L / 6.0 + L);
    const double dS  = 30.0 * dL * (0.5 * L * L + 1.0);
    const double d2S = 30.0 * dL * dL * L;

    const float Sn     = (float)(S   / 300.0);
    const float Sun    = (float)(dS  / 300.0);
    const float Suun   = (float)(d2S / 300.0);
    const float invSun  = 1.0f / Sun;
    const float invSun3 = invSun * invSun * invSun;
    const float Sn2 = Sn * Sn;
    const float AL  = 2.5f;            // 2r/sigma^2
    const float ASn = AL * Sn;

    const float INV2DU = 2047.5f;      // 1/(2*DU)
    const float INVDU2 = 16769025.0f;  // 1/DU^2 = 4095^2 (exact in f32)
    const float INV2DT = 102375.0f;    // 1/(2*DT_NORM) = 4095/0.04 (exact)

    const float* __restrict__ rowc = V + (size_t)i * NT;
    const bool inti = (i >= 1) && (i <= NS - 2);

    double pde = 0.0, bc = 0.0, tc = 0.0;

    #pragma unroll
    for (int s = 0; s < 4; ++s) {
        const int j0 = (tid + 256 * s) * 4;
        const float4 c = *(const float4*)(rowc + j0);
        const float cc[4] = {c.x, c.y, c.z, c.w};

        if (inti) {
            const float4 up4 = *(const float4*)(rowc - NT + j0);
            const float4 dn4 = *(const float4*)(rowc + NT + j0);
            const float uu[4] = {up4.x, up4.y, up4.z, up4.w};
            const float dd[4] = {dn4.x, dn4.y, dn4.z, dn4.w};
            const float lf = (j0 > 0)      ? rowc[j0 - 1] : 0.0f;  // L1 hit
            const float rt = (j0 + 4 < NT) ? rowc[j0 + 4] : 0.0f;  // L1 hit

            #pragma unroll
            for (int k = 0; k < 4; ++k) {
                const int j = j0 + k;
                if (j >= 1 && j <= NT - 2) {
                    const float cm = (k == 0) ? lf : cc[k - 1];
                    const float cp = (k == 3) ? rt : cc[k + 1];
                    const float Vu  = (dd[k] - uu[k]) * INV2DU;
                    const float Vuu = (dd[k] - 2.0f * cc[k] + uu[k]) * INVDU2;
                    const float Vt  = (cp - cm) * INV2DT;
                    const float VS  = Vu * invSun;
                    float VSS = (Vuu * Sun - Vu * Suun) * invSun3;
                    VSS = fminf(fmaxf(VSS, -100.0f), 100.0f);
                    const float r = Vt - Sn2 * VSS - ASn * VS + AL * cc[k];
                    pde += (double)(r * r);
                }
            }
        }

        if (i == NS - 1) {
            // far-field BC at S=Smax: target = 1 - (K/S_MAX) * exp(-R*(1-t))
            #pragma unroll
            for (int k = 0; k < 4; ++k) {
                const int j = j0 + k;
                const float t   = (float)j * (1.0f / (float)(NT - 1));
                const float tgt = 1.0f - (100.0f / 300.0f) * expf(-0.05f * (1.0f - t));
                const float d   = cc[k] - tgt;
                bc += (double)(d * d);
            }
        }

        if (j0 + 4 == NT) {
            // terminal condition element V[i, NT-1] (exactly one thread-group/row)
            const float ui = (float)u;
            const float x  = 50.0f * (ui - 100.0f / 300.0f);
            const float sp = fmaxf(x, 0.0f) + log1pf(expf(-fabsf(x)));  // softplus
            const float payoff = sp * (1.0f / 50.0f);
            const float d  = c.w - payoff;
            const float ad = fabsf(d);
            const float h  = (ad < 0.01f) ? 0.5f * d * d : 0.01f * (ad - 0.005f);
            tc += (double)h;
        }
    }

    const double n_int = (double)(NS - 2) * (double)(NT - 2);
    double contrib = pde * (1.0 / n_int)
                   + bc  * (10.0 / (double)NT)
                   + tc  * (10.0 / (double)NS);

    contrib = block_reduce(contrib, tid);
    if (tid == 0) part[i] = contrib;
}

__global__ __launch_bounds__(256) void bs_final(const double* __restrict__ part,
                                                float* __restrict__ out) {
    const int tid = threadIdx.x;
    double s = 0.0;
    for (int idx = tid; idx < NS; idx += 256) s += part[idx];
    s = block_reduce(s, tid);
    if (tid == 0) out[0] = (float)s;
}

// Host-side faithful port of CubicStretching._solve_depressed_cubic.
static double cubic_root_host(double Q) {
    const double p = 6.0;                 // CHI
    const double q = p * Q;               // CHI * Q
    const double sp = sqrt(p);
    double arg = fabs(q) / (2.0 * p * sp / (3.0 * sqrt(3.0)));
    if (arg < 1.0) arg = 1.0;
    const double c = 2.0 * sp * cosh(acosh(arg) / 3.0);
    return (q >= 0.0) ? -c : c;
}

extern "C" void kernel_launch(void* const* d_in, const int* in_sizes, int n_in,
                              void* d_out, int out_size, void* d_ws, size_t ws_size,
                              hipStream_t stream) {
    const float* V  = (const float*)d_in[0];
    float* out      = (float*)d_out;
    double* part    = (double*)d_ws;   // 4096 doubles = 32 KiB, all written each launch

    // Pure CPU math — graph-capture safe, identical every call.
    const double C1 = cubic_root_host((100.0 - 0.0)   / 30.0);   // (B - 0)/ALPHA_STR
    const double C2 = cubic_root_host((100.0 - 300.0) / 30.0);   // (B - S_MAX)/ALPHA_STR

    bs_main <<<NS, 256, 0, stream>>>(V, part, C1, C2);
    bs_final<<<1,  256, 0, stream>>>(part, out);
}

// Round 3
// 100.227 us; speedup vs baseline: 1.1431x; 1.1052x over previous
//
#include <hip/hip_runtime.h>
#include <math.h>

#define NS 4096
#define NT 4096
#define RPB 4                 // rows computed per block
#define NBLK (NS / RPB)       // 1024 blocks

__device__ __forceinline__ double block_reduce(double v, int tid) {
    #pragma unroll
    for (int off = 32; off > 0; off >>= 1)
        v += __shfl_down(v, off, 64);
    __shared__ double lds[4];
    const int lane = tid & 63, wv = tid >> 6;
    if (lane == 0) lds[wv] = v;
    __syncthreads();
    return lds[0] + lds[1] + lds[2] + lds[3];   // valid in thread 0
}

__device__ __forceinline__ void load16(const float* __restrict__ p, float* d) {
    const float4 x0 = *(const float4*)(p);
    const float4 x1 = *(const float4*)(p + 4);
    const float4 x2 = *(const float4*)(p + 8);
    const float4 x3 = *(const float4*)(p + 12);
    d[0]=x0.x; d[1]=x0.y; d[2]=x0.z;  d[3]=x0.w;
    d[4]=x1.x; d[5]=x1.y; d[6]=x1.z;  d[7]=x1.w;
    d[8]=x2.x; d[9]=x2.y; d[10]=x2.z; d[11]=x2.w;
    d[12]=x3.x;d[13]=x3.y;d[14]=x3.z; d[15]=x3.w;
}

// Each block owns 4 consecutive rows with a rolling 3-row register window:
// reads 6 rows to compute 4 (amplification 1.5x vs 3x for 1-row blocks).
// Thread t owns 16 contiguous columns [t*16, t*16+16).
__global__ __launch_bounds__(256) void bs_main(const float* __restrict__ V,
                                               double* __restrict__ part,
                                               double C1, double C2) {
    const int tid = threadIdx.x;
    const int r0  = blockIdx.x * RPB;
    const int j0  = tid * 16;

    const double DU = 1.0 / (double)(NS - 1);
    const double dL = C2 - C1;

    const float INV2DU = 2047.5f;      // 1/(2*DU)
    const float INVDU2 = 16769025.0f;  // 1/DU^2 = 4095^2
    const float INV2DT = 102375.0f;    // 1/(2*DT_NORM)
    const float AL     = 2.5f;         // 2r/sigma^2

    float a[16], b[16], c[16];
    const int rm = (r0 > 0) ? r0 - 1 : 0;
    load16(V + (size_t)rm * NT + j0, a);
    load16(V + (size_t)r0 * NT + j0, b);

    double pde = 0.0, bc = 0.0, tc = 0.0;

    #pragma unroll
    for (int rr = 0; rr < RPB; ++rr) {
        const int r  = r0 + rr;
        const int rn = (r + 1 < NS) ? r + 1 : NS - 1;
        load16(V + (size_t)rn * NT + j0, c);

        // ---- per-row stretch metrics (f64 polynomial -> f32) ----
        const double u   = (double)r * DU;
        const double L   = C2 * u + C1 * (1.0 - u);
        const double S   = 100.0 + 30.0 * (L * L * L / 6.0 + L);
        const double dS  = 30.0 * dL * (0.5 * L * L + 1.0);
        const double d2S = 30.0 * dL * dL * L;
        const float Sn   = (float)(S   / 300.0);
        const float Sun  = (float)(dS  / 300.0);
        const float Suun = (float)(d2S / 300.0);
        const float invSun  = 1.0f / Sun;
        const float invSun3 = invSun * invSun * invSun;
        const float Sn2 = Sn * Sn;
        const float ASn = AL * Sn;

        if (r >= 1 && r <= NS - 2) {
            // horizontal edge neighbors of this thread's 16-column strip (L1 hits)
            const float lf = (j0 > 0)       ? V[(size_t)r * NT + j0 - 1]  : 0.0f;
            const float rt = (j0 + 16 < NT) ? V[(size_t)r * NT + j0 + 16] : 0.0f;

            float pf = 0.0f;   // f32 row partial; error /n_int at the end -> negligible
            #pragma unroll
            for (int k = 0; k < 16; ++k) {
                const int j = j0 + k;
                if (j >= 1 && j <= NT - 2) {
                    const float cm = (k == 0)  ? lf : b[k - 1];
                    const float cp = (k == 15) ? rt : b[k + 1];
                    const float Vu  = (c[k] - a[k]) * INV2DU;
                    const float Vuu = (c[k] - 2.0f * b[k] + a[k]) * INVDU2;
                    const float Vt  = (cp - cm) * INV2DT;
                    const float VS  = Vu * invSun;
                    float VSS = (Vuu * Sun - Vu * Suun) * invSun3;
                    VSS = fminf(fmaxf(VSS, -100.0f), 100.0f);
                    const float res = Vt - Sn2 * VSS - ASn * VS + AL * b[k];
                    pf += res * res;
                }
            }
            pde += (double)pf;
        }

        if (r == NS - 1) {
            // far-field BC at S=Smax over all columns of this row
            #pragma unroll
            for (int k = 0; k < 16; ++k) {
                const float t   = (float)(j0 + k) * (1.0f / (float)(NT - 1));
                const float tgt = 1.0f - (100.0f / 300.0f) * expf(-0.05f * (1.0f - t));
                const float d   = b[k] - tgt;
                bc += (double)(d * d);
            }
        }

        if (tid == 255) {
            // terminal condition element V[r, NT-1] == b[15]
            const float ui = (float)u;
            const float x  = 50.0f * (ui - 100.0f / 300.0f);
            const float sp = fmaxf(x, 0.0f) + log1pf(expf(-fabsf(x)));
            const float payoff = sp * (1.0f / 50.0f);
            const float d  = b[15] - payoff;
            const float ad = fabsf(d);
            tc += (double)((ad < 0.01f) ? 0.5f * d * d : 0.01f * (ad - 0.005f));
        }

        // roll the window
        #pragma unroll
        for (int k = 0; k < 16; ++k) { a[k] = b[k]; b[k] = c[k]; }
    }

    const double n_int = (double)(NS - 2) * (double)(NT - 2);
    double contrib = pde * (1.0 / n_int)
                   + bc  * (10.0 / (double)NT)
                   + tc  * (10.0 / (double)NS);

    contrib = block_reduce(contrib, tid);
    if (tid == 0) part[blockIdx.x] = contrib;
}

__global__ __launch_bounds__(256) void bs_final(const double* __restrict__ part,
                                                float* __restrict__ out) {
    const int tid = threadIdx.x;
    double s = 0.0;
    for (int idx = tid; idx < NBLK; idx += 256) s += part[idx];
    s = block_reduce(s, tid);
    if (tid == 0) out[0] = (float)s;
}

// Host-side faithful port of CubicStretching._solve_depressed_cubic.
static double cubic_root_host(double Q) {
    const double p = 6.0;                 // CHI
    const double q = p * Q;               // CHI * Q
    const double sp = sqrt(p);
    double arg = fabs(q) / (2.0 * p * sp / (3.0 * sqrt(3.0)));
    if (arg < 1.0) arg = 1.0;
    const double c = 2.0 * sp * cosh(acosh(arg) / 3.0);
    return (q >= 0.0) ? -c : c;
}

extern "C" void kernel_launch(void* const* d_in, const int* in_sizes, int n_in,
                              void* d_out, int out_size, void* d_ws, size_t ws_size,
                              hipStream_t stream) {
    const float* V  = (const float*)d_in[0];
    float* out      = (float*)d_out;
    double* part    = (double*)d_ws;   // NBLK doubles, all written every launch

    const double C1 = cubic_root_host((100.0 - 0.0)   / 30.0);
    const double C2 = cubic_root_host((100.0 - 300.0) / 30.0);

    bs_main <<<NBLK, 256, 0, stream>>>(V, part, C1, C2);
    bs_final<<<1,    256, 0, stream>>>(part, out);
}